// Round 1
// baseline (1376.734 us; speedup 1.0000x reference)
//
#include <hip/hip_runtime.h>
#include <hip/hip_bf16.h>

#define DEV __device__ __forceinline__

DEV unsigned fenc(float f) {
    unsigned u = __float_as_uint(f);
    return (u & 0x80000000u) ? ~u : (u | 0x80000000u);
}
DEV float fdec(unsigned u) {
    return __uint_as_float((u & 0x80000000u) ? (u & 0x7FFFFFFFu) : ~u);
}

// Fused tall-skinny GEMM: for m in [0,NM): er[m] = x_r @ W[m]^T + b[m]   [E,64]
// plus per-edge dot ed[m][e] = er[m][e,:] . ar[m]
// Tile: 64 edges x 64 outs per block, 256 threads, 4x4 per thread, K chunked by 64.
template <int NM>
__global__ __launch_bounds__(256) void gemm_k(
    const float* __restrict__ xr,
    const float* __restrict__ W0, const float* __restrict__ b0, const float* __restrict__ ar0,
    const float* __restrict__ W1, const float* __restrict__ b1, const float* __restrict__ ar1,
    const float* __restrict__ W2, const float* __restrict__ b2, const float* __restrict__ ar2,
    float* __restrict__ er0, float* __restrict__ er1, float* __restrict__ er2,
    float* __restrict__ ed0, float* __restrict__ ed1, float* __restrict__ ed2,
    int E, int K)
{
    __shared__ float At[64 * 64];          // At[k][edge]
    __shared__ float Wt[NM][64 * 64];      // Wt[m][k][j]
    __shared__ float red[NM][16][64];      // er_dot partials [m][jq][edge_local]

    const float* Ws[3]  = {W0, W1, W2};
    const float* bs[3]  = {b0, b1, b2};
    const float* ars[3] = {ar0, ar1, ar2};
    float* ers[3] = {er0, er1, er2};
    float* eds[3] = {ed0, ed1, ed2};

    const int t = threadIdx.x;
    const long e0 = (long)blockIdx.x * 64;
    const int eq = t & 15;       // edge quad 0..15
    const int jq = t >> 4;       // out  quad 0..15
    const int el = t >> 2;       // staging row 0..63
    const int kk = (t & 3) * 16; // staging k base

    float acc[NM][4][4];
#pragma unroll
    for (int m = 0; m < NM; ++m)
#pragma unroll
        for (int i = 0; i < 4; ++i)
#pragma unroll
            for (int j = 0; j < 4; ++j) acc[m][i][j] = 0.f;

    for (int c = 0; c < K; c += 64) {
        // stage A chunk (transposed): At[k][e]
        {
            const long e = e0 + el;
#pragma unroll
            for (int g = 0; g < 4; ++g) {
                float4 v = make_float4(0.f, 0.f, 0.f, 0.f);
                if (e < E) v = *(const float4*)(xr + e * K + c + kk + 4 * g);
                At[(kk + 4 * g + 0) * 64 + el] = v.x;
                At[(kk + 4 * g + 1) * 64 + el] = v.y;
                At[(kk + 4 * g + 2) * 64 + el] = v.z;
                At[(kk + 4 * g + 3) * 64 + el] = v.w;
            }
        }
        // stage W chunks (transposed): Wt[m][k][j], j = el
#pragma unroll
        for (int m = 0; m < NM; ++m) {
#pragma unroll
            for (int g = 0; g < 4; ++g) {
                float4 v = *(const float4*)(Ws[m] + (long)el * K + c + kk + 4 * g);
                Wt[m][(kk + 4 * g + 0) * 64 + el] = v.x;
                Wt[m][(kk + 4 * g + 1) * 64 + el] = v.y;
                Wt[m][(kk + 4 * g + 2) * 64 + el] = v.z;
                Wt[m][(kk + 4 * g + 3) * 64 + el] = v.w;
            }
        }
        __syncthreads();
#pragma unroll 8
        for (int kc = 0; kc < 64; ++kc) {
            const float4 a = *(const float4*)&At[kc * 64 + eq * 4];
#pragma unroll
            for (int m = 0; m < NM; ++m) {
                const float4 w = *(const float4*)&Wt[m][kc * 64 + jq * 4];
                acc[m][0][0] += a.x * w.x; acc[m][0][1] += a.x * w.y;
                acc[m][0][2] += a.x * w.z; acc[m][0][3] += a.x * w.w;
                acc[m][1][0] += a.y * w.x; acc[m][1][1] += a.y * w.y;
                acc[m][1][2] += a.y * w.z; acc[m][1][3] += a.y * w.w;
                acc[m][2][0] += a.z * w.x; acc[m][2][1] += a.z * w.y;
                acc[m][2][2] += a.z * w.z; acc[m][2][3] += a.z * w.w;
                acc[m][3][0] += a.w * w.x; acc[m][3][1] += a.w * w.y;
                acc[m][3][2] += a.w * w.z; acc[m][3][3] += a.w * w.w;
            }
        }
        __syncthreads();
    }

    // epilogue: bias, store er, er_dot partials
#pragma unroll
    for (int m = 0; m < NM; ++m) {
        const float4 bb = *(const float4*)(bs[m] + jq * 4);
        const float4 aa = *(const float4*)(ars[m] + jq * 4);
#pragma unroll
        for (int i = 0; i < 4; ++i) {
            acc[m][i][0] += bb.x; acc[m][i][1] += bb.y;
            acc[m][i][2] += bb.z; acc[m][i][3] += bb.w;
            const long e = e0 + eq * 4 + i;
            if (e < E) {
                float4 o = make_float4(acc[m][i][0], acc[m][i][1], acc[m][i][2], acc[m][i][3]);
                *(float4*)(ers[m] + e * 64 + jq * 4) = o;
            }
            red[m][jq][eq * 4 + i] = acc[m][i][0] * aa.x + acc[m][i][1] * aa.y +
                                     acc[m][i][2] * aa.z + acc[m][i][3] * aa.w;
        }
    }
    __syncthreads();
    if (t < 64) {
        const long e = e0 + t;
        if (e < E) {
#pragma unroll
            for (int m = 0; m < NM; ++m) {
                float sum = 0.f;
#pragma unroll
                for (int q = 0; q < 16; ++q) sum += red[m][q][t];
                eds[m][e] = sum;
            }
        }
    }
}

__global__ __launch_bounds__(256) void init_k(unsigned* __restrict__ menc,
                                              float* __restrict__ s,
                                              float* __restrict__ agg, int N)
{
    const long i = (long)blockIdx.x * 256 + threadIdx.x;
    if (i < (long)N * 64) agg[i] = 0.f;
    if (i < N) { menc[i] = 0u; s[i] = 0.f; }
}

// wave per edge: logits = xe[idx[e]].a_node + ed[e]; leaky-relu; atomicMax segment max
__global__ __launch_bounds__(256) void logits_k(
    const float* __restrict__ xe, const int* __restrict__ idx,
    const float* __restrict__ ed, const float* __restrict__ an,
    float* __restrict__ lr, unsigned* __restrict__ menc, int E)
{
    const int lane = threadIdx.x & 63;
    const long e = (long)blockIdx.x * 4 + (threadIdx.x >> 6);
    if (e >= E) return;
    const int n = idx[e];
    float v = xe[(long)n * 64 + lane] * an[lane];
#pragma unroll
    for (int off = 32; off >= 1; off >>= 1) v += __shfl_xor(v, off, 64);
    if (lane == 0) {
        const float lg = v + ed[e];
        const float l = lg > 0.f ? lg : 0.01f * lg;
        lr[e] = l;
        atomicMax(&menc[n], fenc(l));
    }
}

// wave per edge: ex = exp(lr - m); s[n]+=ex; agg[n][:] += ex*er[rel[e]][:]
__global__ __launch_bounds__(256) void scatter_k(
    const float* __restrict__ lr, const unsigned* __restrict__ menc,
    const int* __restrict__ idx, const int* __restrict__ rel,
    const float* __restrict__ er, float* __restrict__ s,
    float* __restrict__ agg, int E)
{
    const int lane = threadIdx.x & 63;
    const long e = (long)blockIdx.x * 4 + (threadIdx.x >> 6);
    if (e >= E) return;
    const int n = idx[e];
    const float mv = fdec(menc[n]);
    const float ex = __expf(lr[e] - mv);
    if (lane == 0) atomicAdd(&s[n], ex);
    const int r = rel[e];
    atomicAdd(&agg[(long)n * 64 + lane], ex * er[(long)r * 64 + lane]);
}

__global__ __launch_bounds__(256) void update_k(
    float* __restrict__ out, const float* __restrict__ agg,
    const float* __restrict__ s, int N)
{
    const long i = (long)blockIdx.x * 256 + threadIdx.x;
    if (i >= (long)N * 64) return;
    const int n = (int)(i >> 6);
    const float a = agg[i] / (s[n] + 1e-16f);
    out[i] += fmaxf(a, 0.f);
}

extern "C" void kernel_launch(void* const* d_in, const int* in_sizes, int n_in,
                              void* d_out, int out_size, void* d_ws, size_t ws_size,
                              hipStream_t stream)
{
    const float* xe  = (const float*)d_in[0];
    const float* xr  = (const float*)d_in[1];
    const int*   eix = (const int*)d_in[2];
    const int*   rel = (const int*)d_in[3];
    const float* Wr  = (const float*)d_in[4];
    const float* br  = (const float*)d_in[5];
    const float* Wr1 = (const float*)d_in[6];
    const float* br1 = (const float*)d_in[7];
    const float* Wr2 = (const float*)d_in[8];
    const float* br2 = (const float*)d_in[9];
    const float* ah  = (const float*)d_in[10];
    const float* ah1 = (const float*)d_in[11];
    const float* at_ = (const float*)d_in[12];
    const float* ar1 = (const float*)d_in[13];
    const float* ar2 = (const float*)d_in[14];
    const float* ar3 = (const float*)d_in[15];

    const int E = in_sizes[3];
    const int N = in_sizes[0] / 64;
    const int K = in_sizes[1] / E;
    float* out = (float*)d_out;

    char* p = (char*)d_ws;
    auto carve = [&](size_t bytes) -> void* {
        void* r = (void*)p;
        p += (bytes + 255) & ~(size_t)255;
        return r;
    };
    const size_t er_b = (size_t)E * 64 * 4;
    const size_t ed_b = (size_t)E * 4;
    auto al = [](size_t b) { return (b + 255) & ~(size_t)255; };
    const size_t tail = al(ed_b) + 2 * al((size_t)N * 4) + al((size_t)N * 64 * 4);
    const size_t need_fused  = 3 * al(er_b) + 3 * al(ed_b) + tail;
    const bool fused = ws_size >= need_fused;

    float* er[3];
    float* ed[3];
    if (fused) {
        for (int m = 0; m < 3; ++m) er[m] = (float*)carve(er_b);
        for (int m = 0; m < 3; ++m) ed[m] = (float*)carve(ed_b);
    } else {
        float* e_ = (float*)carve(er_b);
        float* d_ = (float*)carve(ed_b);
        for (int m = 0; m < 3; ++m) { er[m] = e_; ed[m] = d_; }
    }
    float* lr = (float*)carve(ed_b);
    unsigned* menc = (unsigned*)carve((size_t)N * 4);
    float* s = (float*)carve((size_t)N * 4);
    float* agg = (float*)carve((size_t)N * 64 * 4);

    hipMemcpyAsync(out, xe, (size_t)N * 64 * 4, hipMemcpyDeviceToDevice, stream);

    const int* idxs[3] = {eix, eix + E, eix};
    const float* an[3]  = {ah, at_, ah1};
    const float* arr[3] = {ar1, ar2, ar3};
    const float* Wm[3]  = {Wr, Wr1, Wr2};
    const float* bm[3]  = {br, br1, br2};

    const int gemm_grid = (E + 63) / 64;
    const int edge_grid = (E + 3) / 4;
    const int node_grid = ((long)N * 64 + 255) / 256;

    if (fused) {
        gemm_k<3><<<gemm_grid, 256, 0, stream>>>(
            xr, Wr, br, ar1, Wr1, br1, ar2, Wr2, br2, ar3,
            er[0], er[1], er[2], ed[0], ed[1], ed[2], E, K);
    }

    for (int b = 0; b < 3; ++b) {
        if (!fused) {
            gemm_k<1><<<gemm_grid, 256, 0, stream>>>(
                xr, Wm[b], bm[b], arr[b], nullptr, nullptr, nullptr,
                nullptr, nullptr, nullptr,
                er[b], nullptr, nullptr, ed[b], nullptr, nullptr, E, K);
        }
        init_k<<<node_grid, 256, 0, stream>>>(menc, s, agg, N);
        logits_k<<<edge_grid, 256, 0, stream>>>(out, idxs[b], ed[b], an[b], lr, menc, E);
        scatter_k<<<edge_grid, 256, 0, stream>>>(lr, menc, idxs[b], rel, er[b], s, agg, E);
        update_k<<<node_grid, 256, 0, stream>>>(out, agg, s, N);
    }
}

// Round 2
// 807.192 us; speedup vs baseline: 1.7056x; 1.7056x over previous
//
#include <hip/hip_runtime.h>
#include <hip/hip_bf16.h>

typedef __attribute__((ext_vector_type(8))) short short8;
typedef __attribute__((ext_vector_type(4))) float f32x4;

#define DEV __device__ __forceinline__

DEV unsigned fenc(float f) {
    unsigned u = __float_as_uint(f);
    return (u & 0x80000000u) ? ~u : (u | 0x80000000u);
}
DEV float fdec(unsigned u) {
    return __uint_as_float((u & 0x80000000u) ? (u & 0x7FFFFFFFu) : ~u);
}
DEV unsigned short f2bf(float f) {
    unsigned u = __float_as_uint(f);
    u += 0x7FFFu + ((u >> 16) & 1u);
    return (unsigned short)(u >> 16);
}
DEV float bf2f(unsigned short h) { return __uint_as_float(((unsigned)h) << 16); }

// ---------------------------------------------------------------------------
// Fused bf16 MFMA GEMM: er_all = x_r @ [W0;W1;W2]^T + b   (f32 in, bf16 out)
// plus per-edge dots ed[m][e] = (er[m][e,:]) . ar[m]
// Tile: 64 edges x 192 outs per block, 256 threads (4 waves), K chunked by 64.
// Wave w owns col-tiles [3w, 3w+3) of 16; rows all 64 (4 row-tiles).
// ---------------------------------------------------------------------------
__global__ __launch_bounds__(256) void gemm_k(
    const float* __restrict__ xr,
    const float* __restrict__ W0, const float* __restrict__ W1, const float* __restrict__ W2,
    const float* __restrict__ b0, const float* __restrict__ b1, const float* __restrict__ b2,
    const float* __restrict__ a0, const float* __restrict__ a1, const float* __restrict__ a2,
    unsigned short* __restrict__ er0, unsigned short* __restrict__ er1, unsigned short* __restrict__ er2,
    float* __restrict__ ed0, float* __restrict__ ed1, float* __restrict__ ed2,
    int E, int K)
{
    __shared__ unsigned short As[64 * 72];   // [row][k] bf16, stride 72 (144B)
    __shared__ unsigned short Wt[192 * 72];  // [gcol][k] bf16
    __shared__ float red[12][64];            // ed partials per col-tile

    const int t = threadIdx.x;
    const int w = t >> 6, l = t & 63;
    const int l15 = l & 15, lg = l >> 4;
    const long e0 = (long)blockIdx.x * 64;
    const int srow = t >> 2, skb = (t & 3) * 16;  // staging: row, k-base

    f32x4 acc[4][3];
#pragma unroll
    for (int rt = 0; rt < 4; ++rt)
#pragma unroll
        for (int i = 0; i < 3; ++i) acc[rt][i] = (f32x4)(0.f);

    for (int c = 0; c < K; c += 64) {
        // ---- stage A chunk (64 rows x 64 k), f32 -> bf16 ----
        {
            const long e = e0 + srow;
            float4 v0 = make_float4(0.f, 0.f, 0.f, 0.f), v1 = v0, v2 = v0, v3 = v0;
            if (e < E) {
                const float* s = xr + e * (long)K + c + skb;
                v0 = *(const float4*)(s);
                v1 = *(const float4*)(s + 4);
                v2 = *(const float4*)(s + 8);
                v3 = *(const float4*)(s + 12);
            }
            short8 o0, o1;
            o0[0] = (short)f2bf(v0.x); o0[1] = (short)f2bf(v0.y);
            o0[2] = (short)f2bf(v0.z); o0[3] = (short)f2bf(v0.w);
            o0[4] = (short)f2bf(v1.x); o0[5] = (short)f2bf(v1.y);
            o0[6] = (short)f2bf(v1.z); o0[7] = (short)f2bf(v1.w);
            o1[0] = (short)f2bf(v2.x); o1[1] = (short)f2bf(v2.y);
            o1[2] = (short)f2bf(v2.z); o1[3] = (short)f2bf(v2.w);
            o1[4] = (short)f2bf(v3.x); o1[5] = (short)f2bf(v3.y);
            o1[6] = (short)f2bf(v3.z); o1[7] = (short)f2bf(v3.w);
            *(short8*)&As[srow * 72 + skb] = o0;
            *(short8*)&As[srow * 72 + skb + 8] = o1;
        }
        // ---- stage W chunk (192 gcols x 64 k), f32 -> bf16 ----
#pragma unroll
        for (int i = 0; i < 3; ++i) {
            const float* Wm = (i == 0) ? W0 : ((i == 1) ? W1 : W2);
            const float* s = Wm + (long)srow * K + c + skb;
            float4 v0 = *(const float4*)(s);
            float4 v1 = *(const float4*)(s + 4);
            float4 v2 = *(const float4*)(s + 8);
            float4 v3 = *(const float4*)(s + 12);
            short8 o0, o1;
            o0[0] = (short)f2bf(v0.x); o0[1] = (short)f2bf(v0.y);
            o0[2] = (short)f2bf(v0.z); o0[3] = (short)f2bf(v0.w);
            o0[4] = (short)f2bf(v1.x); o0[5] = (short)f2bf(v1.y);
            o0[6] = (short)f2bf(v1.z); o0[7] = (short)f2bf(v1.w);
            o1[0] = (short)f2bf(v2.x); o1[1] = (short)f2bf(v2.y);
            o1[2] = (short)f2bf(v2.z); o1[3] = (short)f2bf(v2.w);
            o1[4] = (short)f2bf(v3.x); o1[5] = (short)f2bf(v3.y);
            o1[6] = (short)f2bf(v3.z); o1[7] = (short)f2bf(v3.w);
            *(short8*)&Wt[(i * 64 + srow) * 72 + skb] = o0;
            *(short8*)&Wt[(i * 64 + srow) * 72 + skb + 8] = o1;
        }
        __syncthreads();
        // ---- MFMA: 2 k-steps of 32 ----
#pragma unroll
        for (int ks = 0; ks < 2; ++ks) {
            const int kb = ks * 32 + (lg << 3);
            short8 af[4];
#pragma unroll
            for (int rt = 0; rt < 4; ++rt)
                af[rt] = *(const short8*)&As[(rt * 16 + l15) * 72 + kb];
#pragma unroll
            for (int i = 0; i < 3; ++i) {
                const int gcol = (w * 3 + i) * 16 + l15;
                const short8 bv = *(const short8*)&Wt[gcol * 72 + kb];
#pragma unroll
                for (int rt = 0; rt < 4; ++rt)
                    acc[rt][i] = __builtin_amdgcn_mfma_f32_16x16x32_bf16(af[rt], bv, acc[rt][i], 0, 0, 0);
            }
        }
        __syncthreads();
    }

    // ---- epilogue: bias, bf16 er store, ed partial dots ----
#pragma unroll
    for (int i = 0; i < 3; ++i) {
        const int ct = w * 3 + i;
        const int m = ct >> 2;
        const int cw = ((ct & 3) << 4) + l15;  // col within matrix, 0..63
        const float* bm = (m == 0) ? b0 : ((m == 1) ? b1 : b2);
        const float* am = (m == 0) ? a0 : ((m == 1) ? a1 : a2);
        unsigned short* em = (m == 0) ? er0 : ((m == 1) ? er1 : er2);
        const float bias = bm[cw], av = am[cw];
#pragma unroll
        for (int rt = 0; rt < 4; ++rt) {
#pragma unroll
            for (int j = 0; j < 4; ++j) {
                const int row = rt * 16 + (lg << 2) + j;
                const float v = acc[rt][i][j] + bias;
                const long e = e0 + row;
                if (e < E) em[e * 64 + cw] = f2bf(v);
                float p = v * av;
                p += __shfl_xor(p, 1);
                p += __shfl_xor(p, 2);
                p += __shfl_xor(p, 4);
                p += __shfl_xor(p, 8);
                if (l15 == 0) red[ct][row] = p;
            }
        }
    }
    __syncthreads();
    if (t < 64) {
        const long e = e0 + t;
        if (e < E) {
            ed0[e] = red[0][t] + red[1][t] + red[2][t] + red[3][t];
            ed1[e] = red[4][t] + red[5][t] + red[6][t] + red[7][t];
            ed2[e] = red[8][t] + red[9][t] + red[10][t] + red[11][t];
        }
    }
}

// ---------------------------------------------------------------------------
// Node kernel: (MODE 0) out = xe; (MODE 1,2) out += relu(agg/(s+eps));
// (MODE 0,1) also: pn[n] = out[n].an, zero agg/s/menc for next block.
// One wave per node.
// ---------------------------------------------------------------------------
template <int MODE>
__global__ __launch_bounds__(256) void node_k(
    const float* __restrict__ xe, float* __restrict__ out,
    float* __restrict__ agg, float* __restrict__ s, unsigned* __restrict__ menc,
    float* __restrict__ pn, const float* __restrict__ an, int N)
{
    const int node = blockIdx.x * 4 + (threadIdx.x >> 6);
    if (node >= N) return;
    const int l = threadIdx.x & 63;
    const size_t o = (size_t)node * 64 + l;
    float x;
    if (MODE == 0) {
        x = xe[o];
    } else {
        const float a = agg[o];
        const float d = s[node];
        x = out[o] + fmaxf(a / (d + 1e-16f), 0.f);
    }
    out[o] = x;
    if (MODE < 2) {
        float v = x * an[l];
#pragma unroll
        for (int off = 32; off >= 1; off >>= 1) v += __shfl_xor(v, off);
        agg[o] = 0.f;
        if (l == 0) { pn[node] = v; s[node] = 0.f; menc[node] = 0u; }
    }
}

// thread per edge: leaky-relu logit + segment max via atomicMax on encoded f32
__global__ __launch_bounds__(256) void logits_k(
    const float* __restrict__ pn, const float* __restrict__ ed,
    const int* __restrict__ idx, float* __restrict__ lr,
    unsigned* __restrict__ menc, int E)
{
    const int e = blockIdx.x * 256 + threadIdx.x;
    if (e >= E) return;
    const int n = idx[e];
    const float lg = pn[n] + ed[e];
    const float lv = lg > 0.f ? lg : 0.01f * lg;
    lr[e] = lv;
    atomicMax(&menc[n], fenc(lv));
}

// wave per edge (grid-stride): ex=exp(lr-m); s[n]+=ex; agg[n][:] += ex*er[rel[e]]
__global__ __launch_bounds__(256) void scatter_k(
    const float* __restrict__ lr, const unsigned* __restrict__ menc,
    const int* __restrict__ idx, const int* __restrict__ rel,
    const unsigned short* __restrict__ er, float* __restrict__ s,
    float* __restrict__ agg, int E)
{
    const int l = threadIdx.x & 63;
    const int wid = blockIdx.x * 4 + (threadIdx.x >> 6);
    const int nw = gridDim.x * 4;
    for (int e = wid; e < E; e += nw) {
        const int n = idx[e];
        const float mv = fdec(menc[n]);
        const float ex = __expf(lr[e] - mv);
        const int r = rel[e];
        const float v = ex * bf2f(er[(size_t)r * 64 + l]);
        atomicAdd(agg + (size_t)n * 64 + l, v);
        if (l == 0) atomicAdd(s + n, ex);
    }
}

extern "C" void kernel_launch(void* const* d_in, const int* in_sizes, int n_in,
                              void* d_out, int out_size, void* d_ws, size_t ws_size,
                              hipStream_t stream)
{
    const float* xe  = (const float*)d_in[0];
    const float* xr  = (const float*)d_in[1];
    const int*   eix = (const int*)d_in[2];
    const int*   rel = (const int*)d_in[3];
    const float* Wr  = (const float*)d_in[4];
    const float* br  = (const float*)d_in[5];
    const float* Wr1 = (const float*)d_in[6];
    const float* br1 = (const float*)d_in[7];
    const float* Wr2 = (const float*)d_in[8];
    const float* br2 = (const float*)d_in[9];
    const float* ah  = (const float*)d_in[10];
    const float* ah1 = (const float*)d_in[11];
    const float* at_ = (const float*)d_in[12];
    const float* ar1 = (const float*)d_in[13];
    const float* ar2 = (const float*)d_in[14];
    const float* ar3 = (const float*)d_in[15];

    const int E = in_sizes[3];
    const int N = in_sizes[0] / 64;
    const int K = in_sizes[1] / E;
    float* out = (float*)d_out;

    char* p = (char*)d_ws;
    auto carve = [&](size_t bytes) -> void* {
        void* r = (void*)p;
        p += (bytes + 255) & ~(size_t)255;
        return r;
    };
    unsigned short* er[3];
    float* ed[3];
    for (int m = 0; m < 3; ++m) er[m] = (unsigned short*)carve((size_t)E * 64 * 2);
    for (int m = 0; m < 3; ++m) ed[m] = (float*)carve((size_t)E * 4);
    float* lr = (float*)carve((size_t)E * 4);
    float* pn = (float*)carve((size_t)N * 4);
    unsigned* menc = (unsigned*)carve((size_t)N * 4);
    float* s = (float*)carve((size_t)N * 4);
    float* agg = (float*)carve((size_t)N * 64 * 4);
    (void)ws_size;

    const int* idxs[3] = {eix, eix + E, eix};

    const int gemm_grid = (E + 63) / 64;
    const int node_grid = (N + 3) / 4;
    const int lg_grid   = (E + 255) / 256;

    gemm_k<<<gemm_grid, 256, 0, stream>>>(
        xr, Wr, Wr1, Wr2, br, br1, br2, ar1, ar2, ar3,
        er[0], er[1], er[2], ed[0], ed[1], ed[2], E, K);

    node_k<0><<<node_grid, 256, 0, stream>>>(xe, out, agg, s, menc, pn, ah, N);

    for (int b = 0; b < 3; ++b) {
        logits_k<<<lg_grid, 256, 0, stream>>>(pn, ed[b], idxs[b], lr, menc, E);
        scatter_k<<<2048, 256, 0, stream>>>(lr, menc, idxs[b], rel, er[b], s, agg, E);
        if (b == 0)
            node_k<1><<<node_grid, 256, 0, stream>>>(xe, out, agg, s, menc, pn, at_, N);
        else if (b == 1)
            node_k<1><<<node_grid, 256, 0, stream>>>(xe, out, agg, s, menc, pn, ah1, N);
        else
            node_k<2><<<node_grid, 256, 0, stream>>>(xe, out, agg, s, menc, pn, ah, N);
    }
}

// Round 4
// 797.605 us; speedup vs baseline: 1.7261x; 1.0120x over previous
//
#include <hip/hip_runtime.h>
#include <hip/hip_bf16.h>

typedef __attribute__((ext_vector_type(8))) short short8;
typedef __attribute__((ext_vector_type(4))) float f32x4;

#define DEV __device__ __forceinline__

DEV unsigned short f2bf(float f) {
    unsigned u = __float_as_uint(f);
    u += 0x7FFFu + ((u >> 16) & 1u);
    return (unsigned short)(u >> 16);
}
DEV float bf2f(unsigned short h) { return __uint_as_float(((unsigned)h) << 16); }
DEV unsigned pk2(float lo, float hi) {
    float2 f; f.x = lo; f.y = hi;
    __hip_bfloat162 h = __float22bfloat162_rn(f);
    unsigned r; __builtin_memcpy(&r, &h, 4);
    return r;
}
union S8 { short8 s; unsigned u[4]; };

// ---------------------------------------------------------------------------
// W pre-convert: wbf[gcol][k] bf16, gcol = m*64 + out_row, k in [0,192)
// ---------------------------------------------------------------------------
__global__ __launch_bounds__(256) void wconv_k(
    const float* __restrict__ W0, const float* __restrict__ W1,
    const float* __restrict__ W2, unsigned short* __restrict__ wbf)
{
    const int i = blockIdx.x * 256 + threadIdx.x;
    if (i >= 3 * 64 * 192) return;
    const int m = i / (64 * 192), r = i % (64 * 192);
    const float* W = (m == 0) ? W0 : ((m == 1) ? W1 : W2);
    wbf[i] = f2bf(W[r]);
}

// ---------------------------------------------------------------------------
// bf16 MFMA GEMM: er[e][0:192] = x_r[e] @ [W0;W1;W2]^T + b  (bf16 out)
// ed[m][e] = er[m-slice][e] . ar[m]
// 64-edge x 192-out tile, 4 waves; B-fragments resident in registers.
// A LDS [64][192] bf16, XOR-swizzled (byte ^= (row&7)<<4).
// ---------------------------------------------------------------------------
__global__ __launch_bounds__(256) void gemm_k(
    const float* __restrict__ xr, const unsigned short* __restrict__ wbf,
    const float* __restrict__ b0, const float* __restrict__ b1, const float* __restrict__ b2,
    const float* __restrict__ a0, const float* __restrict__ a1, const float* __restrict__ a2,
    unsigned short* __restrict__ er,
    float* __restrict__ ed0, float* __restrict__ ed1, float* __restrict__ ed2,
    int E, int ntiles, int K)
{
    __shared__ unsigned short As[64 * 192];
    __shared__ float red[12][64];
    const int t = threadIdx.x;
    const int w = t >> 6, l = t & 63, l15 = l & 15, lg = l >> 4;
    const int srow = t >> 2, sq = t & 3;

    // B fragments: wave w owns col-tiles [3w, 3w+3)
    short8 bf[3][6];
#pragma unroll
    for (int i = 0; i < 3; ++i) {
        const int gc = (w * 3 + i) * 16 + l15;
#pragma unroll
        for (int ks = 0; ks < 6; ++ks)
            bf[i][ks] = *(const short8*)&wbf[(size_t)gc * 192 + ks * 32 + lg * 8];
    }
    float biasv[3], av[3];
#pragma unroll
    for (int i = 0; i < 3; ++i) {
        const int ct = w * 3 + i, m = ct >> 2, cw = ((ct & 3) << 4) + l15;
        const float* bp = (m == 0) ? b0 : ((m == 1) ? b1 : b2);
        const float* ap = (m == 0) ? a0 : ((m == 1) ? a1 : a2);
        biasv[i] = bp[cw];
        av[i] = ap[cw];
    }

    for (int tile = blockIdx.x; tile < ntiles; tile += gridDim.x) {
        const long e0 = (long)tile * 64;
        const long e = e0 + srow;
        __syncthreads();  // protect As from previous tile's readers
        // ---- stage A: 48 f32 per thread (one row-quarter), 3 rounds ----
#pragma unroll
        for (int r = 0; r < 3; ++r) {
            const int kb = sq * 48 + r * 16;
            float4 v0 = make_float4(0.f, 0.f, 0.f, 0.f), v1 = v0, v2 = v0, v3 = v0;
            if (e < E) {
                const float* sp = xr + e * (long)K + kb;
                v0 = *(const float4*)(sp);
                v1 = *(const float4*)(sp + 4);
                v2 = *(const float4*)(sp + 8);
                v3 = *(const float4*)(sp + 12);
            }
            S8 o0, o1;
            o0.u[0] = pk2(v0.x, v0.y); o0.u[1] = pk2(v0.z, v0.w);
            o0.u[2] = pk2(v1.x, v1.y); o0.u[3] = pk2(v1.z, v1.w);
            o1.u[0] = pk2(v2.x, v2.y); o1.u[1] = pk2(v2.z, v2.w);
            o1.u[2] = pk2(v3.x, v3.y); o1.u[3] = pk2(v3.z, v3.w);
            const unsigned byte0 = (unsigned)(srow * 384 + kb * 2);
            const unsigned swz = (unsigned)((srow & 7) << 4);
            *(short8*)((char*)As + (byte0 ^ swz)) = o0.s;
            *(short8*)((char*)As + ((byte0 + 16) ^ swz)) = o1.s;
        }
        __syncthreads();
        // ---- MFMA ----
        f32x4 acc[4][3];
#pragma unroll
        for (int rt = 0; rt < 4; ++rt)
#pragma unroll
            for (int i = 0; i < 3; ++i) acc[rt][i] = (f32x4)(0.f);
#pragma unroll
        for (int ks = 0; ks < 6; ++ks) {
            short8 af[4];
#pragma unroll
            for (int rt = 0; rt < 4; ++rt) {
                const int row = rt * 16 + l15;
                const unsigned byte = (unsigned)(row * 384 + ks * 64 + lg * 16);
                af[rt] = *(const short8*)((const char*)As + (byte ^ ((row & 7) << 4)));
            }
#pragma unroll
            for (int i = 0; i < 3; ++i)
#pragma unroll
                for (int rt = 0; rt < 4; ++rt)
                    acc[rt][i] = __builtin_amdgcn_mfma_f32_16x16x32_bf16(af[rt], bf[i][ks], acc[rt][i], 0, 0, 0);
        }
        __syncthreads();
        // ---- epilogue: bias, transpose into As (bf16), ed partials ----
#pragma unroll
        for (int i = 0; i < 3; ++i) {
            const int gc = (w * 3 + i) * 16 + l15;
#pragma unroll
            for (int rt = 0; rt < 4; ++rt)
#pragma unroll
                for (int j = 0; j < 4; ++j) {
                    const int grow = rt * 16 + (lg << 2) + j;
                    const float v = acc[rt][i][j] + biasv[i];
                    const unsigned byte = (unsigned)(grow * 384 + gc * 2);
                    *(unsigned short*)((char*)As + (byte ^ ((grow & 7) << 4))) = f2bf(v);
                    float p = v * av[i];
                    p += __shfl_xor(p, 1);
                    p += __shfl_xor(p, 2);
                    p += __shfl_xor(p, 4);
                    p += __shfl_xor(p, 8);
                    if (l15 == 0) red[w * 3 + i][grow] = p;
                }
        }
        __syncthreads();
        // ---- coalesced er store: 64 rows x 24 chunks = 1536 x 16B, 6 rounds ----
#pragma unroll
        for (int r = 0; r < 6; ++r) {
            const int chunk = r * 256 + t;
            const int row = chunk / 24, cpos = chunk - row * 24;
            const long ee = e0 + row;
            if (ee < E) {
                const unsigned byte = (unsigned)(chunk * 16);
                short8 v = *(const short8*)((const char*)As + (byte ^ ((row & 7) << 4)));
                *(short8*)((char*)er + ((size_t)ee * 384 + cpos * 16)) = v;
            }
        }
        if (t < 64) {
            const long ee = e0 + t;
            if (ee < E) {
                float s0 = 0.f, s1 = 0.f, s2 = 0.f;
#pragma unroll
                for (int q = 0; q < 4; ++q) {
                    s0 += red[q][t]; s1 += red[4 + q][t]; s2 += red[8 + q][t];
                }
                ed0[ee] = s0; ed1[ee] = s1; ed2[ee] = s2;
            }
        }
    }
}

// ---------------------------------------------------------------------------
// CSR build
// ---------------------------------------------------------------------------
__global__ __launch_bounds__(256) void count_k(const int* __restrict__ idx,
                                               int* __restrict__ deg, int E)
{
    const int e = blockIdx.x * 256 + threadIdx.x;
    if (e < E) atomicAdd(&deg[idx[e]], 1);
}

__global__ __launch_bounds__(256) void scan1_k(const int* __restrict__ deg,
                                               int* __restrict__ incl,
                                               int* __restrict__ bsum, int N)
{
    __shared__ int buf[256];
    const int tid = threadIdx.x;
    const int n = blockIdx.x * 256 + tid;
    buf[tid] = (n < N) ? deg[n] : 0;
    __syncthreads();
    for (int d = 1; d < 256; d <<= 1) {
        int v = (tid >= d) ? buf[tid - d] : 0;
        __syncthreads();
        buf[tid] += v;
        __syncthreads();
    }
    if (n < N) incl[n] = buf[tid];
    if (tid == 255) bsum[blockIdx.x] = buf[255];
}

__global__ __launch_bounds__(256) void scan2_k(int* __restrict__ bsum, int nb)
{
    __shared__ int buf[256];
    __shared__ int carry;
    const int tid = threadIdx.x;
    if (tid == 0) carry = 0;
    __syncthreads();
    for (int base = 0; base < nb; base += 256) {
        const int i = base + tid;
        buf[tid] = (i < nb) ? bsum[i] : 0;
        __syncthreads();
        for (int d = 1; d < 256; d <<= 1) {
            int v = (tid >= d) ? buf[tid - d] : 0;
            __syncthreads();
            buf[tid] += v;
            __syncthreads();
        }
        const int c = carry;
        if (i < nb) bsum[i] = buf[tid] + c;
        __syncthreads();
        if (tid == 0) carry = c + buf[255];
        __syncthreads();
    }
}

__global__ __launch_bounds__(256) void off_k(const int* __restrict__ deg,
                                             const int* __restrict__ incl,
                                             const int* __restrict__ bsum,
                                             int* __restrict__ off,
                                             int* __restrict__ cur, int N, int E)
{
    const int n = blockIdx.x * 256 + threadIdx.x;
    if (n < N) {
        const int prev = (blockIdx.x > 0) ? bsum[blockIdx.x - 1] : 0;
        const int o = prev + incl[n] - deg[n];
        off[n] = o;
        cur[n] = o;
    }
    if (n == 0) off[N] = E;
}

__global__ __launch_bounds__(256) void fill_k(const int* __restrict__ idx,
                                              int* __restrict__ cur,
                                              int* __restrict__ elist, int E)
{
    const int e = blockIdx.x * 256 + threadIdx.x;
    if (e >= E) return;
    const int p = atomicAdd(&cur[idx[e]], 1);
    elist[p] = e;
}

// ---------------------------------------------------------------------------
// init: out = xe, pn = xe . an   (wave per node)
// ---------------------------------------------------------------------------
__global__ __launch_bounds__(256) void initn_k(const float* __restrict__ xe,
                                               float* __restrict__ out,
                                               float* __restrict__ pn,
                                               const float* __restrict__ an, int N)
{
    const int node = blockIdx.x * 4 + (threadIdx.x >> 6);
    if (node >= N) return;
    const int l = threadIdx.x & 63;
    const size_t o = (size_t)node * 64 + l;
    const float x = xe[o];
    out[o] = x;
    float v = x * an[l];
#pragma unroll
    for (int d = 1; d < 64; d <<= 1) v += __shfl_xor(v, d);
    if (l == 0) pn[node] = v;
}

// ---------------------------------------------------------------------------
// Fused GAT block: wave per node. Online softmax over the node's CSR edge
// list, weighted er-gather accumulate, node update, next block's pn dot.
// ---------------------------------------------------------------------------
template <int LAST>
__global__ __launch_bounds__(256) void gat_k(
    const int* __restrict__ off, const int* __restrict__ elist,
    const float* __restrict__ ed, const float* __restrict__ pn_in,
    const unsigned short* __restrict__ er, int cb,
    float* __restrict__ out, const float* __restrict__ an_next,
    float* __restrict__ pn_out, int N)
{
    const int node = blockIdx.x * 4 + (threadIdx.x >> 6);
    if (node >= N) return;
    const int l = threadIdx.x & 63;
    const int s0 = off[node], s1 = off[node + 1];
    const float pv = pn_in[node];

    // phase 1: lane-parallel online max/sum over edges
    float m = -1e30f, s = 0.f;
    for (int j = s0 + l; j < s1; j += 64) {
        const int e = elist[j];
        const float lg = pv + ed[e];
        const float lv = lg > 0.f ? lg : 0.01f * lg;
        const float nm = fmaxf(m, lv);
        s = s * __expf(m - nm) + __expf(lv - nm);
        m = nm;
    }
#pragma unroll
    for (int d = 1; d < 64; d <<= 1) {
        const float om = __shfl_xor(m, d), os = __shfl_xor(s, d);
        const float nm = fmaxf(m, om);
        s = s * __expf(m - nm) + os * __expf(om - nm);
        m = nm;
    }
    // phase 2: lane = feature, serial over edges
    float acc = 0.f;
    for (int j = s0; j < s1; ++j) {
        const int e = elist[j];
        const float lg = pv + ed[e];
        const float lv = lg > 0.f ? lg : 0.01f * lg;
        const float ex = __expf(lv - m);
        acc += ex * bf2f(er[(size_t)e * 192 + cb + l]);
    }
    const size_t o = (size_t)node * 64 + l;
    const float x = out[o] + fmaxf(acc / (s + 1e-16f), 0.f);
    out[o] = x;
    if (!LAST) {
        float v = x * an_next[l];
#pragma unroll
        for (int d = 1; d < 64; d <<= 1) v += __shfl_xor(v, d);
        if (l == 0) pn_out[node] = v;
    }
}

extern "C" void kernel_launch(void* const* d_in, const int* in_sizes, int n_in,
                              void* d_out, int out_size, void* d_ws, size_t ws_size,
                              hipStream_t stream)
{
    const float* xe  = (const float*)d_in[0];
    const float* xr  = (const float*)d_in[1];
    const int*   eix = (const int*)d_in[2];
    const float* Wr  = (const float*)d_in[4];
    const float* br  = (const float*)d_in[5];
    const float* Wr1 = (const float*)d_in[6];
    const float* br1 = (const float*)d_in[7];
    const float* Wr2 = (const float*)d_in[8];
    const float* br2 = (const float*)d_in[9];
    const float* ah  = (const float*)d_in[10];
    const float* ah1 = (const float*)d_in[11];
    const float* at_ = (const float*)d_in[12];
    const float* ar1 = (const float*)d_in[13];
    const float* ar2 = (const float*)d_in[14];
    const float* ar3 = (const float*)d_in[15];

    const int E = in_sizes[3];
    const int N = in_sizes[0] / 64;
    const int K = in_sizes[1] / E;
    float* out = (float*)d_out;

    char* p = (char*)d_ws;
    auto carve = [&](size_t bytes) -> void* {
        void* r = (void*)p;
        p += (bytes + 255) & ~(size_t)255;
        return r;
    };
    const int nb = (N + 255) / 256;
    unsigned short* er = (unsigned short*)carve((size_t)E * 192 * 2);
    float* ed0 = (float*)carve((size_t)E * 4);
    float* ed1 = (float*)carve((size_t)E * 4);
    float* ed2 = (float*)carve((size_t)E * 4);
    float* pn = (float*)carve((size_t)N * 4);
    unsigned short* wbf = (unsigned short*)carve((size_t)3 * 64 * 192 * 2);
    int* off_h = (int*)carve((size_t)(N + 1) * 4);
    int* off_t = (int*)carve((size_t)(N + 1) * 4);
    int* el_h = (int*)carve((size_t)E * 4);
    int* el_t = (int*)carve((size_t)E * 4);
    int* deg = (int*)carve((size_t)N * 4);
    int* incl = (int*)carve((size_t)N * 4);
    int* cur = (int*)carve((size_t)N * 4);
    int* bsum = (int*)carve((size_t)nb * 4);
    (void)ws_size;

    const int Eg = (E + 255) / 256;
    const int ng = (N + 3) / 4;
    const int ntiles = (E + 63) / 64;
    const int ggrid = ntiles < 2048 ? ntiles : 2048;

    wconv_k<<<(3 * 64 * 192 + 255) / 256, 256, 0, stream>>>(Wr, Wr1, Wr2, wbf);

    // CSR for h (blocks 0 and 2)
    hipMemsetAsync(deg, 0, (size_t)N * 4, stream);
    count_k<<<Eg, 256, 0, stream>>>(eix, deg, E);
    scan1_k<<<nb, 256, 0, stream>>>(deg, incl, bsum, N);
    scan2_k<<<1, 256, 0, stream>>>(bsum, nb);
    off_k<<<nb, 256, 0, stream>>>(deg, incl, bsum, off_h, cur, N, E);
    fill_k<<<Eg, 256, 0, stream>>>(eix, cur, el_h, E);
    // CSR for t (block 1)
    hipMemsetAsync(deg, 0, (size_t)N * 4, stream);
    count_k<<<Eg, 256, 0, stream>>>(eix + E, deg, E);
    scan1_k<<<nb, 256, 0, stream>>>(deg, incl, bsum, N);
    scan2_k<<<1, 256, 0, stream>>>(bsum, nb);
    off_k<<<nb, 256, 0, stream>>>(deg, incl, bsum, off_t, cur, N, E);
    fill_k<<<Eg, 256, 0, stream>>>(eix + E, cur, el_t, E);

    gemm_k<<<ggrid, 256, 0, stream>>>(xr, wbf, br, br1, br2, ar1, ar2, ar3,
                                      er, ed0, ed1, ed2, E, ntiles, K);

    initn_k<<<ng, 256, 0, stream>>>(xe, out, pn, ah, N);
    gat_k<0><<<ng, 256, 0, stream>>>(off_h, el_h, ed0, pn, er, 0, out, at_, pn, N);
    gat_k<0><<<ng, 256, 0, stream>>>(off_t, el_t, ed1, pn, er, 64, out, ah1, pn, N);
    gat_k<1><<<ng, 256, 0, stream>>>(off_h, el_h, ed2, pn, er, 128, out, nullptr, nullptr, N);
}

// Round 5
// 675.934 us; speedup vs baseline: 2.0368x; 1.1800x over previous
//
#include <hip/hip_runtime.h>
#include <hip/hip_bf16.h>

typedef __attribute__((ext_vector_type(8))) short short8;
typedef __attribute__((ext_vector_type(4))) float f32x4;

#define DEV __device__ __forceinline__

// LDS-only barrier: drains ds ops, leaves global (vmcnt) prefetch in flight.
#define WGBAR() asm volatile("s_waitcnt lgkmcnt(0)\ns_barrier" ::: "memory")

DEV unsigned short f2bf(float f) {
    unsigned u = __float_as_uint(f);
    u += 0x7FFFu + ((u >> 16) & 1u);
    return (unsigned short)(u >> 16);
}
DEV float bf2f(unsigned short h) { return __uint_as_float(((unsigned)h) << 16); }
DEV unsigned pk2(float lo, float hi) {
    float2 f; f.x = lo; f.y = hi;
    __hip_bfloat162 h = __float22bfloat162_rn(f);
    unsigned r; __builtin_memcpy(&r, &h, 4);
    return r;
}
union S8 { short8 s; unsigned u[4]; };

// ---------------------------------------------------------------------------
// W pre-convert: wbf[gcol][k] bf16, gcol = m*64 + out_row, k in [0,192)
// ---------------------------------------------------------------------------
__global__ __launch_bounds__(256) void wconv_k(
    const float* __restrict__ W0, const float* __restrict__ W1,
    const float* __restrict__ W2, unsigned short* __restrict__ wbf)
{
    const int i = blockIdx.x * 256 + threadIdx.x;
    if (i >= 3 * 64 * 192) return;
    const int m = i / (64 * 192), r = i % (64 * 192);
    const float* W = (m == 0) ? W0 : ((m == 1) ? W1 : W2);
    wbf[i] = f2bf(W[r]);
}

// ---------------------------------------------------------------------------
// bf16 MFMA GEMM, software-pipelined:
//   er[e][0:192] = x_r[e] @ [W0;W1;W2]^T + b   (bf16 out)
//   ed[m][e]     = er[m-slice][e] . ar[m]
// 64-edge x 192-out tile, 4 waves; B-fragments resident in registers.
// Double-buffered A LDS (bf16, XOR-swizzled); next tile's A prefetched to
// registers before the barrier; barriers are LDS-only (vmcnt never drained).
// ---------------------------------------------------------------------------
__global__ __launch_bounds__(256) void gemm_k(
    const float* __restrict__ xr, const unsigned short* __restrict__ wbf,
    const float* __restrict__ b0, const float* __restrict__ b1, const float* __restrict__ b2,
    const float* __restrict__ a0, const float* __restrict__ a1, const float* __restrict__ a2,
    unsigned short* __restrict__ er,
    float* __restrict__ ed0, float* __restrict__ ed1, float* __restrict__ ed2,
    int E, int ntiles, int K)
{
    __shared__ unsigned short As[2][64 * 192];
    __shared__ float red[12][64];
    const int t = threadIdx.x;
    const int w = t >> 6, l = t & 63, l15 = l & 15, lg = l >> 4;
    const int srow = t >> 2, sq = t & 3;

    // B fragments: wave w owns col-tiles [3w, 3w+3)
    short8 bfr[3][6];
#pragma unroll
    for (int i = 0; i < 3; ++i) {
        const int gc = (w * 3 + i) * 16 + l15;
#pragma unroll
        for (int ks = 0; ks < 6; ++ks)
            bfr[i][ks] = *(const short8*)&wbf[(size_t)gc * 192 + ks * 32 + lg * 8];
    }
    float biasv[3], av[3];
#pragma unroll
    for (int i = 0; i < 3; ++i) {
        const int ct = w * 3 + i, m = ct >> 2, cw = ((ct & 3) << 4) + l15;
        const float* bp = (m == 0) ? b0 : ((m == 1) ? b1 : b2);
        const float* ap = (m == 0) ? a0 : ((m == 1) ? a1 : a2);
        biasv[i] = bp[cw];
        av[i] = ap[cw];
    }

    float4 nv[12];
    int tile = blockIdx.x;
    // prologue prefetch
    if (tile < ntiles) {
        const long e = (long)tile * 64 + srow;
        const bool ok = e < E;
        const float* sp = xr + e * (long)K + sq * 48;
#pragma unroll
        for (int r = 0; r < 3; ++r)
#pragma unroll
            for (int g = 0; g < 4; ++g)
                nv[r * 4 + g] = ok ? *(const float4*)(sp + r * 16 + g * 4)
                                   : make_float4(0.f, 0.f, 0.f, 0.f);
    }

    int cur = 0;
    for (; tile < ntiles; tile += gridDim.x, cur ^= 1) {
        const long e0 = (long)tile * 64;
        char* Abase = (char*)As[cur];
        // ---- convert prefetched regs -> As[cur] (bf16, swizzled) ----
        {
            const unsigned swz = (unsigned)((srow & 7) << 4);
#pragma unroll
            for (int r = 0; r < 3; ++r) {
                S8 o0, o1;
                o0.u[0] = pk2(nv[r * 4 + 0].x, nv[r * 4 + 0].y);
                o0.u[1] = pk2(nv[r * 4 + 0].z, nv[r * 4 + 0].w);
                o0.u[2] = pk2(nv[r * 4 + 1].x, nv[r * 4 + 1].y);
                o0.u[3] = pk2(nv[r * 4 + 1].z, nv[r * 4 + 1].w);
                o1.u[0] = pk2(nv[r * 4 + 2].x, nv[r * 4 + 2].y);
                o1.u[1] = pk2(nv[r * 4 + 2].z, nv[r * 4 + 2].w);
                o1.u[2] = pk2(nv[r * 4 + 3].x, nv[r * 4 + 3].y);
                o1.u[3] = pk2(nv[r * 4 + 3].z, nv[r * 4 + 3].w);
                const unsigned byte0 = (unsigned)(srow * 384 + (sq * 48 + r * 16) * 2);
                *(short8*)(Abase + (byte0 ^ swz)) = o0.s;
                *(short8*)(Abase + ((byte0 + 16) ^ swz)) = o1.s;
            }
        }
        // ---- issue next tile's loads (stay in flight across barriers) ----
        {
            const long tn = (long)tile + gridDim.x;
            if (tn < ntiles) {
                const long e = tn * 64 + srow;
                const bool ok = e < E;
                const float* sp = xr + e * (long)K + sq * 48;
#pragma unroll
                for (int r = 0; r < 3; ++r)
#pragma unroll
                    for (int g = 0; g < 4; ++g)
                        nv[r * 4 + g] = ok ? *(const float4*)(sp + r * 16 + g * 4)
                                           : make_float4(0.f, 0.f, 0.f, 0.f);
            }
        }
        WGBAR();  // (A) staging visible
        // ---- MFMA ----
        f32x4 acc[4][3];
#pragma unroll
        for (int rt = 0; rt < 4; ++rt)
#pragma unroll
            for (int i = 0; i < 3; ++i) acc[rt][i] = (f32x4)(0.f);
#pragma unroll
        for (int ks = 0; ks < 6; ++ks) {
            short8 af[4];
#pragma unroll
            for (int rt = 0; rt < 4; ++rt) {
                const int row = rt * 16 + l15;
                const unsigned byte = (unsigned)(row * 384 + ks * 64 + lg * 16);
                af[rt] = *(const short8*)((const char*)Abase + (byte ^ ((row & 7) << 4)));
            }
#pragma unroll
            for (int i = 0; i < 3; ++i)
#pragma unroll
                for (int rt = 0; rt < 4; ++rt)
                    acc[rt][i] = __builtin_amdgcn_mfma_f32_16x16x32_bf16(af[rt], bfr[i][ks], acc[rt][i], 0, 0, 0);
        }
        WGBAR();  // (B) all MFMA reads of As[cur] complete
        // ---- epilogue: bias, transpose into As[cur], ed partials ----
#pragma unroll
        for (int i = 0; i < 3; ++i) {
            const int gc = (w * 3 + i) * 16 + l15;
#pragma unroll
            for (int rt = 0; rt < 4; ++rt)
#pragma unroll
                for (int j = 0; j < 4; ++j) {
                    const int grow = rt * 16 + (lg << 2) + j;
                    const float v = acc[rt][i][j] + biasv[i];
                    const unsigned byte = (unsigned)(grow * 384 + gc * 2);
                    *(unsigned short*)(Abase + (byte ^ ((grow & 7) << 4))) = f2bf(v);
                    float p = v * av[i];
                    p += __shfl_xor(p, 1);
                    p += __shfl_xor(p, 2);
                    p += __shfl_xor(p, 4);
                    p += __shfl_xor(p, 8);
                    if (l15 == 0) red[w * 3 + i][grow] = p;
                }
        }
        WGBAR();  // (C) transpose visible
        // ---- coalesced er store: 64 rows x 24 chunks = 1536 x 16B ----
#pragma unroll
        for (int r = 0; r < 6; ++r) {
            const int chunk = r * 256 + t;
            const int row = chunk / 24, cpos = chunk - row * 24;
            const long ee = e0 + row;
            if (ee < E) {
                const unsigned byte = (unsigned)(chunk * 16);
                short8 v = *(const short8*)((const char*)Abase + (byte ^ ((row & 7) << 4)));
                *(short8*)((char*)er + ((size_t)ee * 384 + cpos * 16)) = v;
            }
        }
        if (t < 64) {
            const long ee = e0 + t;
            if (ee < E) {
                float s0 = 0.f, s1 = 0.f, s2 = 0.f;
#pragma unroll
                for (int q = 0; q < 4; ++q) {
                    s0 += red[q][t]; s1 += red[4 + q][t]; s2 += red[8 + q][t];
                }
                ed0[ee] = s0; ed1[ee] = s1; ed2[ee] = s2;
            }
        }
    }
}

// ---------------------------------------------------------------------------
// Fused CSR build over 2N segments: h-graph at [0,N), t-graph at [N,2N)
// ---------------------------------------------------------------------------
__global__ __launch_bounds__(256) void count2_k(const int* __restrict__ h,
                                                const int* __restrict__ tt,
                                                int* __restrict__ deg, int E, int N)
{
    const int e = blockIdx.x * 256 + threadIdx.x;
    if (e >= E) return;
    atomicAdd(&deg[h[e]], 1);
    atomicAdd(&deg[N + tt[e]], 1);
}

__global__ __launch_bounds__(256) void scan1_k(const int* __restrict__ deg,
                                               int* __restrict__ incl,
                                               int* __restrict__ bsum, int M)
{
    __shared__ int buf[256];
    const int tid = threadIdx.x;
    const int n = blockIdx.x * 256 + tid;
    buf[tid] = (n < M) ? deg[n] : 0;
    __syncthreads();
    for (int d = 1; d < 256; d <<= 1) {
        int v = (tid >= d) ? buf[tid - d] : 0;
        __syncthreads();
        buf[tid] += v;
        __syncthreads();
    }
    if (n < M) incl[n] = buf[tid];
    if (tid == 255) bsum[blockIdx.x] = buf[255];
}

__global__ __launch_bounds__(256) void scan2_k(int* __restrict__ bsum, int nb)
{
    __shared__ int buf[256];
    __shared__ int carry;
    const int tid = threadIdx.x;
    if (tid == 0) carry = 0;
    __syncthreads();
    for (int base = 0; base < nb; base += 256) {
        const int i = base + tid;
        buf[tid] = (i < nb) ? bsum[i] : 0;
        __syncthreads();
        for (int d = 1; d < 256; d <<= 1) {
            int v = (tid >= d) ? buf[tid - d] : 0;
            __syncthreads();
            buf[tid] += v;
            __syncthreads();
        }
        const int c = carry;
        if (i < nb) bsum[i] = buf[tid] + c;
        __syncthreads();
        if (tid == 0) carry = c + buf[255];
        __syncthreads();
    }
}

__global__ __launch_bounds__(256) void off_k(const int* __restrict__ deg,
                                             const int* __restrict__ incl,
                                             const int* __restrict__ bsum,
                                             int* __restrict__ off,
                                             int* __restrict__ cur, int M, int tot)
{
    const int n = blockIdx.x * 256 + threadIdx.x;
    if (n < M) {
        const int prev = (blockIdx.x > 0) ? bsum[blockIdx.x - 1] : 0;
        const int o = prev + incl[n] - deg[n];
        off[n] = o;
        cur[n] = o;
    }
    if (n == 0) off[M] = tot;
}

__global__ __launch_bounds__(256) void fill2_k(const int* __restrict__ h,
                                               const int* __restrict__ tt,
                                               int* __restrict__ cur,
                                               int* __restrict__ elist, int E, int N)
{
    const int e = blockIdx.x * 256 + threadIdx.x;
    if (e >= E) return;
    const int p = atomicAdd(&cur[h[e]], 1);
    elist[p] = e;
    const int p2 = atomicAdd(&cur[N + tt[e]], 1);
    elist[p2] = e;
}

// ---------------------------------------------------------------------------
// init: out = xe, pn = xe . an   (wave per node)
// ---------------------------------------------------------------------------
__global__ __launch_bounds__(256) void initn_k(const float* __restrict__ xe,
                                               float* __restrict__ out,
                                               float* __restrict__ pn,
                                               const float* __restrict__ an, int N)
{
    const int node = blockIdx.x * 4 + (threadIdx.x >> 6);
    if (node >= N) return;
    const int l = threadIdx.x & 63;
    const size_t o = (size_t)node * 64 + l;
    const float x = xe[o];
    out[o] = x;
    float v = x * an[l];
#pragma unroll
    for (int d = 1; d < 64; d <<= 1) v += __shfl_xor(v, d);
    if (l == 0) pn[node] = v;
}

// ---------------------------------------------------------------------------
// Fused GAT block: wave per node. Phase 1: lane-parallel online softmax
// stats. Phase 2: 8 edges in parallel (8 lane-groups x short8=16B loads),
// per-wave LDS exchange to recombine features. Then node update + next pn.
// ---------------------------------------------------------------------------
template <int LAST>
__global__ __launch_bounds__(256) void gat_k(
    const int* __restrict__ off, const int* __restrict__ elist,
    const float* __restrict__ ed, const float* __restrict__ pn_in,
    const unsigned short* __restrict__ er, int cb,
    float* __restrict__ out, const float* __restrict__ an_next,
    float* __restrict__ pn_out, int N)
{
    __shared__ float sm[4][8][64];
    const int wv = threadIdx.x >> 6;
    const int node = blockIdx.x * 4 + wv;
    if (node >= N) return;
    const int l = threadIdx.x & 63;
    const int s0 = off[node], s1 = off[node + 1];
    const float pv = pn_in[node];

    // phase 1: lane-parallel online max/sum
    float m = -1e30f, s = 0.f;
    for (int j = s0 + l; j < s1; j += 64) {
        const int e = elist[j];
        const float lg = pv + ed[e];
        const float lv = lg > 0.f ? lg : 0.01f * lg;
        const float nm = fmaxf(m, lv);
        s = s * __expf(m - nm) + __expf(lv - nm);
        m = nm;
    }
#pragma unroll
    for (int d = 1; d < 64; d <<= 1) {
        const float om = __shfl_xor(m, d), os = __shfl_xor(s, d);
        const float nm = fmaxf(m, om);
        s = s * __expf(m - nm) + os * __expf(om - nm);
        m = nm;
    }

    // phase 2: 8 edges in parallel; lane-group g handles edge j+g,
    // lane q within group loads features [q*8, q*8+8) as short8 (16B).
    const int g = l >> 3, q = l & 7;
    f32x4 acA = (f32x4)(0.f), acB = (f32x4)(0.f);
    for (int j = s0; j < s1; j += 8) {
        const int jj = j + g;
        if (jj < s1) {
            const int e = elist[jj];
            const float lg = pv + ed[e];
            const float lv = lg > 0.f ? lg : 0.01f * lg;
            const float wgt = __expf(lv - m);
            const short8 v = *(const short8*)(er + (size_t)e * 192 + cb + q * 8);
            acA[0] += wgt * bf2f((unsigned short)v[0]);
            acA[1] += wgt * bf2f((unsigned short)v[1]);
            acA[2] += wgt * bf2f((unsigned short)v[2]);
            acA[3] += wgt * bf2f((unsigned short)v[3]);
            acB[0] += wgt * bf2f((unsigned short)v[4]);
            acB[1] += wgt * bf2f((unsigned short)v[5]);
            acB[2] += wgt * bf2f((unsigned short)v[6]);
            acB[3] += wgt * bf2f((unsigned short)v[7]);
        }
    }
    *(f32x4*)&sm[wv][g][q * 8] = acA;
    *(f32x4*)&sm[wv][g][q * 8 + 4] = acB;
    asm volatile("s_waitcnt lgkmcnt(0)" ::: "memory");  // wave-internal exchange
    float a = 0.f;
#pragma unroll
    for (int gg = 0; gg < 8; ++gg) a += sm[wv][gg][l];

    const size_t o = (size_t)node * 64 + l;
    const float x = out[o] + fmaxf(a / (s + 1e-16f), 0.f);
    out[o] = x;
    if (!LAST) {
        float v = x * an_next[l];
#pragma unroll
        for (int d = 1; d < 64; d <<= 1) v += __shfl_xor(v, d);
        if (l == 0) pn_out[node] = v;
    }
}

extern "C" void kernel_launch(void* const* d_in, const int* in_sizes, int n_in,
                              void* d_out, int out_size, void* d_ws, size_t ws_size,
                              hipStream_t stream)
{
    const float* xe  = (const float*)d_in[0];
    const float* xr  = (const float*)d_in[1];
    const int*   eix = (const int*)d_in[2];
    const float* Wr  = (const float*)d_in[4];
    const float* br  = (const float*)d_in[5];
    const float* Wr1 = (const float*)d_in[6];
    const float* br1 = (const float*)d_in[7];
    const float* Wr2 = (const float*)d_in[8];
    const float* br2 = (const float*)d_in[9];
    const float* ah  = (const float*)d_in[10];
    const float* ah1 = (const float*)d_in[11];
    const float* at_ = (const float*)d_in[12];
    const float* ar1 = (const float*)d_in[13];
    const float* ar2 = (const float*)d_in[14];
    const float* ar3 = (const float*)d_in[15];

    const int E = in_sizes[3];
    const int N = in_sizes[0] / 64;
    const int K = in_sizes[1] / E;
    const int M = 2 * N;
    float* out = (float*)d_out;

    char* p = (char*)d_ws;
    auto carve = [&](size_t bytes) -> void* {
        void* r = (void*)p;
        p += (bytes + 255) & ~(size_t)255;
        return r;
    };
    const int nb = (M + 255) / 256;
    unsigned short* er = (unsigned short*)carve((size_t)E * 192 * 2);
    float* ed0 = (float*)carve((size_t)E * 4);
    float* ed1 = (float*)carve((size_t)E * 4);
    float* ed2 = (float*)carve((size_t)E * 4);
    float* pn = (float*)carve((size_t)N * 4);
    unsigned short* wbf = (unsigned short*)carve((size_t)3 * 64 * 192 * 2);
    int* off = (int*)carve((size_t)(M + 1) * 4);
    int* elist = (int*)carve((size_t)2 * E * 4);
    int* deg = (int*)carve((size_t)M * 4);
    int* incl = (int*)carve((size_t)M * 4);
    int* cur = (int*)carve((size_t)M * 4);
    int* bsum = (int*)carve((size_t)nb * 4);
    (void)ws_size;

    const int Eg = (E + 255) / 256;
    const int ng = (N + 3) / 4;
    const int ntiles = (E + 63) / 64;
    const int ggrid = ntiles < 1536 ? ntiles : 1536;

    wconv_k<<<(3 * 64 * 192 + 255) / 256, 256, 0, stream>>>(Wr, Wr1, Wr2, wbf);

    hipMemsetAsync(deg, 0, (size_t)M * 4, stream);
    count2_k<<<Eg, 256, 0, stream>>>(eix, eix + E, deg, E, N);
    scan1_k<<<nb, 256, 0, stream>>>(deg, incl, bsum, M);
    scan2_k<<<1, 256, 0, stream>>>(bsum, nb);
    off_k<<<nb, 256, 0, stream>>>(deg, incl, bsum, off, cur, M, 2 * E);
    fill2_k<<<Eg, 256, 0, stream>>>(eix, eix + E, cur, elist, E, N);

    gemm_k<<<ggrid, 256, 0, stream>>>(xr, wbf, br, br1, br2, ar1, ar2, ar3,
                                      er, ed0, ed1, ed2, E, ntiles, K);

    initn_k<<<ng, 256, 0, stream>>>(xe, out, pn, ah, N);
    gat_k<0><<<ng, 256, 0, stream>>>(off, elist, ed0, pn, er, 0, out, at_, pn, N);
    gat_k<0><<<ng, 256, 0, stream>>>(off + N, elist, ed1, pn, er, 64, out, ah1, pn, N);
    gat_k<1><<<ng, 256, 0, stream>>>(off, elist, ed2, pn, er, 128, out, nullptr, nullptr, N);
}

// Round 6
// 481.924 us; speedup vs baseline: 2.8567x; 1.4026x over previous
//
#include <hip/hip_runtime.h>
#include <hip/hip_bf16.h>

typedef __attribute__((ext_vector_type(8))) short short8;
typedef __attribute__((ext_vector_type(4))) float f32x4;

#define DEV __device__ __forceinline__

DEV unsigned short f2bf(float f) {
    unsigned u = __float_as_uint(f);
    u += 0x7FFFu + ((u >> 16) & 1u);
    return (unsigned short)(u >> 16);
}
DEV float bf2f(unsigned short h) { return __uint_as_float(((unsigned)h) << 16); }
DEV unsigned pk2(float lo, float hi) {
    float2 f; f.x = lo; f.y = hi;
    __hip_bfloat162 h = __float22bfloat162_rn(f);
    unsigned r; __builtin_memcpy(&r, &h, 4);
    return r;
}
union S8 { short8 s; unsigned u[4]; };

// ---------------------------------------------------------------------------
// W pre-convert: wbf[gcol][k] bf16, gcol = m*64 + out_row, k in [0,192)
// ---------------------------------------------------------------------------
__global__ __launch_bounds__(256) void wconv_k(
    const float* __restrict__ W0, const float* __restrict__ W1,
    const float* __restrict__ W2, unsigned short* __restrict__ wbf)
{
    const int i = blockIdx.x * 256 + threadIdx.x;
    if (i >= 3 * 64 * 192) return;
    const int m = i / (64 * 192), r = i % (64 * 192);
    const float* W = (m == 0) ? W0 : ((m == 1) ? W1 : W2);
    wbf[i] = f2bf(W[r]);
}

// ---------------------------------------------------------------------------
// bf16 MFMA GEMM (swapped operands -> features-in-registers output):
//   er[e][0:192] = x_r[e] @ [W0;W1;W2]^T + b   (bf16, direct packed stores)
//   ed[m][e]     = er[m-slice][e] . ar[m]      (in-register dot + 2 shuffles)
// 64-edge x 192-out tile, 4 waves; W fragments register-resident.
// A staged in LDS (bf16, XOR swizzle byte^=(row&7)<<4). 3 barriers/tile.
// ---------------------------------------------------------------------------
__global__ __launch_bounds__(256) void gemm_k(
    const float* __restrict__ xr, const unsigned short* __restrict__ wbf,
    const float* __restrict__ b0, const float* __restrict__ b1, const float* __restrict__ b2,
    const float* __restrict__ a0, const float* __restrict__ a1, const float* __restrict__ a2,
    unsigned short* __restrict__ er,
    float* __restrict__ ed0, float* __restrict__ ed1, float* __restrict__ ed2,
    int E, int ntiles, int K)
{
    __shared__ unsigned short As[64 * 192];
    __shared__ float red[12][64];
    const int t = threadIdx.x;
    const int w = t >> 6, l = t & 63, l15 = l & 15, lg = l >> 4;
    const int srow = t >> 2, sq = t & 3;

    // W fragments (A-operand of swapped mfma): lane l15 -> feature row of tile
    short8 bfr[3][6];
#pragma unroll
    for (int i = 0; i < 3; ++i) {
        const int gc = (w * 3 + i) * 16 + l15;
#pragma unroll
        for (int ks = 0; ks < 6; ++ks)
            bfr[i][ks] = *(const short8*)&wbf[(size_t)gc * 192 + ks * 32 + lg * 8];
    }
    // bias / ar for this thread's 4 features per col-tile: f = (w*3+i)*16 + lg*4 + j
    float4 biasf[3], arf[3];
#pragma unroll
    for (int i = 0; i < 3; ++i) {
        const int ct = w * 3 + i, m = ct >> 2;
        const int cb_ = ((ct & 3) << 4) + (lg << 2);
        const float* bp = (m == 0) ? b0 : ((m == 1) ? b1 : b2);
        const float* ap = (m == 0) ? a0 : ((m == 1) ? a1 : a2);
        biasf[i] = *(const float4*)(bp + cb_);
        arf[i]  = *(const float4*)(ap + cb_);
    }

    for (int tile = blockIdx.x; tile < ntiles; tile += gridDim.x) {
        const long e0 = (long)tile * 64;
        __syncthreads();  // As/red reuse guard
        // ---- stage A: 48 f32 per thread, convert to bf16, swizzled LDS ----
        {
            const long e = e0 + srow;
            const bool ok = e < E;
            const float* sp = xr + e * (long)K + sq * 48;
            const unsigned swz = (unsigned)((srow & 7) << 4);
#pragma unroll
            for (int r = 0; r < 3; ++r) {
                float4 v0 = make_float4(0.f, 0.f, 0.f, 0.f), v1 = v0, v2 = v0, v3 = v0;
                if (ok) {
                    v0 = *(const float4*)(sp + r * 16);
                    v1 = *(const float4*)(sp + r * 16 + 4);
                    v2 = *(const float4*)(sp + r * 16 + 8);
                    v3 = *(const float4*)(sp + r * 16 + 12);
                }
                S8 o0, o1;
                o0.u[0] = pk2(v0.x, v0.y); o0.u[1] = pk2(v0.z, v0.w);
                o0.u[2] = pk2(v1.x, v1.y); o0.u[3] = pk2(v1.z, v1.w);
                o1.u[0] = pk2(v2.x, v2.y); o1.u[1] = pk2(v2.z, v2.w);
                o1.u[2] = pk2(v3.x, v3.y); o1.u[3] = pk2(v3.z, v3.w);
                const unsigned byte0 = (unsigned)(srow * 384 + (sq * 48 + r * 16) * 2);
                *(short8*)((char*)As + (byte0 ^ swz)) = o0.s;
                *(short8*)((char*)As + ((byte0 + 16) ^ swz)) = o1.s;
            }
        }
        __syncthreads();
        // ---- MFMA (swapped: D col=edge, row=feature) ----
        f32x4 acc[4][3];
#pragma unroll
        for (int rt = 0; rt < 4; ++rt)
#pragma unroll
            for (int i = 0; i < 3; ++i) acc[rt][i] = (f32x4)(0.f);
#pragma unroll
        for (int ks = 0; ks < 6; ++ks) {
            short8 af[4];
#pragma unroll
            for (int rt = 0; rt < 4; ++rt) {
                const int row = rt * 16 + l15;
                const unsigned byte = (unsigned)(row * 384 + ks * 64 + lg * 16);
                af[rt] = *(const short8*)((const char*)As + (byte ^ ((row & 7) << 4)));
            }
#pragma unroll
            for (int i = 0; i < 3; ++i)
#pragma unroll
                for (int rt = 0; rt < 4; ++rt)
                    acc[rt][i] = __builtin_amdgcn_mfma_f32_16x16x32_bf16(bfr[i][ks], af[rt], acc[rt][i], 0, 0, 0);
        }
        // ---- epilogue: bias, direct packed er store, in-reg ed dot ----
#pragma unroll
        for (int i = 0; i < 3; ++i) {
            const int fb = (w * 3 + i) * 16 + (lg << 2);  // feature base of this quad
#pragma unroll
            for (int rt = 0; rt < 4; ++rt) {
                const int edge = rt * 16 + l15;
                const long ee = e0 + edge;
                const float v0 = acc[rt][i][0] + biasf[i].x;
                const float v1 = acc[rt][i][1] + biasf[i].y;
                const float v2 = acc[rt][i][2] + biasf[i].z;
                const float v3 = acc[rt][i][3] + biasf[i].w;
                if (ee < E) {
                    uint2 pk;
                    pk.x = pk2(v0, v1);
                    pk.y = pk2(v2, v3);
                    *(uint2*)(er + (size_t)ee * 192 + fb) = pk;
                }
                float p = v0 * arf[i].x + v1 * arf[i].y + v2 * arf[i].z + v3 * arf[i].w;
                p += __shfl_xor(p, 16);
                p += __shfl_xor(p, 32);
                if (lg == 0) red[w * 3 + i][edge] = p;
            }
        }
        __syncthreads();  // red visible
        if (t < 64) {
            const long ee = e0 + t;
            if (ee < E) {
                float s0 = 0.f, s1 = 0.f, s2 = 0.f;
#pragma unroll
                for (int q = 0; q < 4; ++q) {
                    s0 += red[q][t]; s1 += red[4 + q][t]; s2 += red[8 + q][t];
                }
                ed0[ee] = s0; ed1[ee] = s1; ed2[ee] = s2;
            }
        }
    }
}

// ---------------------------------------------------------------------------
// Fused CSR build over 2N segments: h-graph at [0,N), t-graph at [N,2N)
// ---------------------------------------------------------------------------
__global__ __launch_bounds__(256) void count2_k(const int* __restrict__ h,
                                                const int* __restrict__ tt,
                                                int* __restrict__ deg, int E, int N)
{
    const int e = blockIdx.x * 256 + threadIdx.x;
    if (e >= E) return;
    atomicAdd(&deg[h[e]], 1);
    atomicAdd(&deg[N + tt[e]], 1);
}

__global__ __launch_bounds__(256) void scan1_k(const int* __restrict__ deg,
                                               int* __restrict__ incl,
                                               int* __restrict__ bsum, int M)
{
    __shared__ int buf[256];
    const int tid = threadIdx.x;
    const int n = blockIdx.x * 256 + tid;
    buf[tid] = (n < M) ? deg[n] : 0;
    __syncthreads();
    for (int d = 1; d < 256; d <<= 1) {
        int v = (tid >= d) ? buf[tid - d] : 0;
        __syncthreads();
        buf[tid] += v;
        __syncthreads();
    }
    if (n < M) incl[n] = buf[tid];
    if (tid == 255) bsum[blockIdx.x] = buf[255];
}

__global__ __launch_bounds__(256) void scan2_k(int* __restrict__ bsum, int nb)
{
    __shared__ int buf[256];
    __shared__ int carry;
    const int tid = threadIdx.x;
    if (tid == 0) carry = 0;
    __syncthreads();
    for (int base = 0; base < nb; base += 256) {
        const int i = base + tid;
        buf[tid] = (i < nb) ? bsum[i] : 0;
        __syncthreads();
        for (int d = 1; d < 256; d <<= 1) {
            int v = (tid >= d) ? buf[tid - d] : 0;
            __syncthreads();
            buf[tid] += v;
            __syncthreads();
        }
        const int c = carry;
        if (i < nb) bsum[i] = buf[tid] + c;
        __syncthreads();
        if (tid == 0) carry = c + buf[255];
        __syncthreads();
    }
}

__global__ __launch_bounds__(256) void off_k(const int* __restrict__ deg,
                                             const int* __restrict__ incl,
                                             const int* __restrict__ bsum,
                                             int* __restrict__ off,
                                             int* __restrict__ cur, int M, int tot)
{
    const int n = blockIdx.x * 256 + threadIdx.x;
    if (n < M) {
        const int prev = (blockIdx.x > 0) ? bsum[blockIdx.x - 1] : 0;
        const int o = prev + incl[n] - deg[n];
        off[n] = o;
        cur[n] = o;
    }
    if (n == 0) off[M] = tot;
}

__global__ __launch_bounds__(256) void fill2_k(const int* __restrict__ h,
                                               const int* __restrict__ tt,
                                               int* __restrict__ cur,
                                               int* __restrict__ elist, int E, int N)
{
    const int e = blockIdx.x * 256 + threadIdx.x;
    if (e >= E) return;
    const int p = atomicAdd(&cur[h[e]], 1);
    elist[p] = e;
    const int p2 = atomicAdd(&cur[N + tt[e]], 1);
    elist[p2] = e;
}

// ---------------------------------------------------------------------------
// init: out = xe, pn = xe . an   (wave per node)
// ---------------------------------------------------------------------------
__global__ __launch_bounds__(256) void initn_k(const float* __restrict__ xe,
                                               float* __restrict__ out,
                                               float* __restrict__ pn,
                                               const float* __restrict__ an, int N)
{
    const int node = blockIdx.x * 4 + (threadIdx.x >> 6);
    if (node >= N) return;
    const int l = threadIdx.x & 63;
    const size_t o = (size_t)node * 64 + l;
    const float x = xe[o];
    out[o] = x;
    float v = x * an[l];
#pragma unroll
    for (int d = 1; d < 64; d <<= 1) v += __shfl_xor(v, d);
    if (l == 0) pn[node] = v;
}

// ---------------------------------------------------------------------------
// Fused GAT block: wave per node. Phase 1: lane-parallel online softmax
// stats. Phase 2: 8 edges in parallel (8 lane-groups x short8=16B loads),
// per-wave LDS exchange to recombine features. Then node update + next pn.
// ---------------------------------------------------------------------------
template <int LAST>
__global__ __launch_bounds__(256) void gat_k(
    const int* __restrict__ off, const int* __restrict__ elist,
    const float* __restrict__ ed, const float* __restrict__ pn_in,
    const unsigned short* __restrict__ er, int cb,
    float* __restrict__ out, const float* __restrict__ an_next,
    float* __restrict__ pn_out, int N)
{
    __shared__ float sm[4][8][64];
    const int wv = threadIdx.x >> 6;
    const int node = blockIdx.x * 4 + wv;
    if (node >= N) return;
    const int l = threadIdx.x & 63;
    const int s0 = off[node], s1 = off[node + 1];
    const float pv = pn_in[node];

    // phase 1: lane-parallel online max/sum
    float m = -1e30f, s = 0.f;
    for (int j = s0 + l; j < s1; j += 64) {
        const int e = elist[j];
        const float lg = pv + ed[e];
        const float lv = lg > 0.f ? lg : 0.01f * lg;
        const float nm = fmaxf(m, lv);
        s = s * __expf(m - nm) + __expf(lv - nm);
        m = nm;
    }
#pragma unroll
    for (int d = 1; d < 64; d <<= 1) {
        const float om = __shfl_xor(m, d), os = __shfl_xor(s, d);
        const float nm = fmaxf(m, om);
        s = s * __expf(m - nm) + os * __expf(om - nm);
        m = nm;
    }

    // phase 2: 8 edges in parallel; lane-group g handles edge j+g,
    // lane q within group loads features [q*8, q*8+8) as short8 (16B).
    const int g = l >> 3, q = l & 7;
    f32x4 acA = (f32x4)(0.f), acB = (f32x4)(0.f);
    for (int j = s0; j < s1; j += 8) {
        const int jj = j + g;
        if (jj < s1) {
            const int e = elist[jj];
            const float lg = pv + ed[e];
            const float lv = lg > 0.f ? lg : 0.01f * lg;
            const float wgt = __expf(lv - m);
            const short8 v = *(const short8*)(er + (size_t)e * 192 + cb + q * 8);
            acA[0] += wgt * bf2f((unsigned short)v[0]);
            acA[1] += wgt * bf2f((unsigned short)v[1]);
            acA[2] += wgt * bf2f((unsigned short)v[2]);
            acA[3] += wgt * bf2f((unsigned short)v[3]);
            acB[0] += wgt * bf2f((unsigned short)v[4]);
            acB[1] += wgt * bf2f((unsigned short)v[5]);
            acB[2] += wgt * bf2f((unsigned short)v[6]);
            acB[3] += wgt * bf2f((unsigned short)v[7]);
        }
    }
    *(f32x4*)&sm[wv][g][q * 8] = acA;
    *(f32x4*)&sm[wv][g][q * 8 + 4] = acB;
    asm volatile("s_waitcnt lgkmcnt(0)" ::: "memory");  // wave-internal exchange
    float a = 0.f;
#pragma unroll
    for (int gg = 0; gg < 8; ++gg) a += sm[wv][gg][l];

    const size_t o = (size_t)node * 64 + l;
    const float x = out[o] + fmaxf(a / (s + 1e-16f), 0.f);
    out[o] = x;
    if (!LAST) {
        float v = x * an_next[l];
#pragma unroll
        for (int d = 1; d < 64; d <<= 1) v += __shfl_xor(v, d);
        if (l == 0) pn_out[node] = v;
    }
}

extern "C" void kernel_launch(void* const* d_in, const int* in_sizes, int n_in,
                              void* d_out, int out_size, void* d_ws, size_t ws_size,
                              hipStream_t stream)
{
    const float* xe  = (const float*)d_in[0];
    const float* xr  = (const float*)d_in[1];
    const int*   eix = (const int*)d_in[2];
    const float* Wr  = (const float*)d_in[4];
    const float* br  = (const float*)d_in[5];
    const float* Wr1 = (const float*)d_in[6];
    const float* br1 = (const float*)d_in[7];
    const float* Wr2 = (const float*)d_in[8];
    const float* br2 = (const float*)d_in[9];
    const float* ah  = (const float*)d_in[10];
    const float* ah1 = (const float*)d_in[11];
    const float* at_ = (const float*)d_in[12];
    const float* ar1 = (const float*)d_in[13];
    const float* ar2 = (const float*)d_in[14];
    const float* ar3 = (const float*)d_in[15];

    const int E = in_sizes[3];
    const int N = in_sizes[0] / 64;
    const int K = in_sizes[1] / E;
    const int M = 2 * N;
    float* out = (float*)d_out;

    char* p = (char*)d_ws;
    auto carve = [&](size_t bytes) -> void* {
        void* r = (void*)p;
        p += (bytes + 255) & ~(size_t)255;
        return r;
    };
    const int nb = (M + 255) / 256;
    unsigned short* er = (unsigned short*)carve((size_t)E * 192 * 2);
    float* ed0 = (float*)carve((size_t)E * 4);
    float* ed1 = (float*)carve((size_t)E * 4);
    float* ed2 = (float*)carve((size_t)E * 4);
    float* pn = (float*)carve((size_t)N * 4);
    unsigned short* wbf = (unsigned short*)carve((size_t)3 * 64 * 192 * 2);
    int* off = (int*)carve((size_t)(M + 1) * 4);
    int* elist = (int*)carve((size_t)2 * E * 4);
    int* deg = (int*)carve((size_t)M * 4);
    int* incl = (int*)carve((size_t)M * 4);
    int* cur = (int*)carve((size_t)M * 4);
    int* bsum = (int*)carve((size_t)nb * 4);
    (void)ws_size;

    const int Eg = (E + 255) / 256;
    const int ng = (N + 3) / 4;
    const int ntiles = (E + 63) / 64;
    const int ggrid = ntiles < 2048 ? ntiles : 2048;

    wconv_k<<<(3 * 64 * 192 + 255) / 256, 256, 0, stream>>>(Wr, Wr1, Wr2, wbf);

    hipMemsetAsync(deg, 0, (size_t)M * 4, stream);
    count2_k<<<Eg, 256, 0, stream>>>(eix, eix + E, deg, E, N);
    scan1_k<<<nb, 256, 0, stream>>>(deg, incl, bsum, M);
    scan2_k<<<1, 256, 0, stream>>>(bsum, nb);
    off_k<<<nb, 256, 0, stream>>>(deg, incl, bsum, off, cur, M, 2 * E);
    fill2_k<<<Eg, 256, 0, stream>>>(eix, eix + E, cur, elist, E, N);

    gemm_k<<<ggrid, 256, 0, stream>>>(xr, wbf, br, br1, br2, ar1, ar2, ar3,
                                      er, ed0, ed1, ed2, E, ntiles, K);

    initn_k<<<ng, 256, 0, stream>>>(xe, out, pn, ah, N);
    gat_k<0><<<ng, 256, 0, stream>>>(off, elist, ed0, pn, er, 0, out, at_, pn, N);
    gat_k<0><<<ng, 256, 0, stream>>>(off + N, elist, ed1, pn, er, 64, out, ah1, pn, N);
    gat_k<1><<<ng, 256, 0, stream>>>(off, elist, ed2, pn, er, 128, out, nullptr, nullptr, N);
}